// Round 20
// baseline (805.928 us; speedup 1.0000x reference)
//
#include <hip/hip_runtime.h>
#include <cstdint>
#include <cstddef>

#define DEV __device__ __forceinline__

namespace {

constexpr int kN = 784, kC = 768, kH = 12, kD = 64;
constexpr int kM = 6272, kOC = 2304, kBH = 96;
constexpr int kNp = 832;                 // padded row length for V^T
constexpr int kMaxFlips = 4096;
constexpr int kMaxUCols = 512;
constexpr size_t SZ_QKV1 = (size_t)kBH * kN * kD;
constexpr size_t SZ_VT   = (size_t)kBH * kD * kNp;
constexpr double kEps   = 2.0e-3;        // activation-round dither
constexpr double kEpsW  = 3.0e-5;        // weight-round dither
constexpr double kEpsX0 = 3.0e-5;        // x0 floor dither
constexpr long long kDS = 1024;          // np-f32 exp_sum ambiguity band
constexpr long long kEP = 128;           // np-f32 (p*factor) product ulp band
constexpr double kGuard = 1.0e-9;        // fast-path vs exact-path boundary guard

using i32x4 = __attribute__((ext_vector_type(4))) int;

DEV void mfma_i8_acc(i32x4& c, i32x4 a, i32x4 b) {
  c = __builtin_amdgcn_mfma_i32_16x16x64_i8(a, b, c, 0, 0, 0);
}

DEV double wave_max_d(double v) {
  for (int o = 32; o; o >>= 1) v = fmax(v, __shfl_xor(v, o));
  return v;
}
DEV int wave_max_i(int v) {
  for (int o = 32; o; o >>= 1) v = max(v, __shfl_xor(v, o));
  return v;
}

// ctl: [0] u64 dbl max|h| ; [8] int max|qk| ; [12] int flipCount ;
// [16] u64 dbl max|proj| ; [24] u64 dbl max|pv| ; [32] int ucount
DEV double ctl_hmax(const char* c)  { return __longlong_as_double(*(const long long*)(c)); }
DEV int    ctl_qkmax(const char* c) { return *(const int*)(c + 8); }
DEV double ctl_pmax(const char* c)  { return __longlong_as_double(*(const long long*)(c + 16)); }
DEV double ctl_pvmax(const char* c) { return __longlong_as_double(*(const long long*)(c + 24)); }

DEV double get_s1(const char* c) { return ctl_hmax(c) / 127.0; }
DEV double get_sa(const char* c) {
  double s1 = get_s1(c);
  double amax = ((double)ctl_qkmax(c) * (s1 * s1)) * 0.125;
  return amax / 127.0;
}
DEV double get_c2(const char* c) { return get_s1(c) * 3.0517578125e-05; }
DEV double get_so(const char* c) { return (ctl_pvmax(c) * get_c2(c)) / 127.0; }

// shift-exp of int_softmax, exact integer form via round-up magic division.
// xi <= 0, x0i < 0, m15 = 15*x0i, magicM = ceil(2^32 / (-x0i)). Exact for n <= 15d.
DEV int p_eval_m(int xi, int x0i, int m15, unsigned long long magicM) {
  int x2 = xi + (xi >> 1) - (xi >> 4);
  x2 = max(x2, m15);
  unsigned long long n = (unsigned long long)(unsigned)(-x2);
  int q = (int)((n * magicM) >> 32);
  int rrem = x2 - x0i * q;
  int base = rrem - 2 * x0i;
  return (q <= 14) ? (base << (14 - q)) : (base >> 1);
}

// Integer 4*P version of r12's p_final — bit-identical values.
DEV int p4_final(long long p, long long fLo, long long fHi) {
  long long a = (p * fLo - kEP) >> 16;
  long long b = (p * fLo + kEP) >> 16;
  if (fLo == fHi) return (int)((a + b) << 1);
  long long c = (p * fHi - kEP) >> 16;
  long long d = (p * fHi + kEP) >> 16;
  return (int)(a + b + c + d);
}

// ------- weight quantization: shared scale, dithered A/B ints + flip record -------
__global__ __launch_bounds__(256) void k_quant_w(
    const float* __restrict__ Wq, const float* __restrict__ Wp,
    const float* __restrict__ s_in_p,
    int8_t* __restrict__ wq8A, int8_t* __restrict__ wq8B,
    int8_t* __restrict__ wp8A, int8_t* __restrict__ wp8B,
    double* __restrict__ outs_q, double* __restrict__ wsp,
    char* __restrict__ ctl, int4* __restrict__ flips) {
  int r = blockIdx.x;
  bool isq = r < kOC;
  const float* row = isq ? Wq + (size_t)r * kC : Wp + (size_t)(r - kOC) * kC;
  double m = 0.0;
  for (int i = threadIdx.x; i < kC; i += 256) m = fmax(m, fabs((double)row[i]));
  m = wave_max_d(m);
  __shared__ double sred[4];
  __shared__ double s_ws;
  if ((threadIdx.x & 63) == 0) sred[threadIdx.x >> 6] = m;
  __syncthreads();
  if (threadIdx.x == 0) {
    double mm = fmax(fmax(sred[0], sred[1]), fmax(sred[2], sred[3]));
    double ws = mm / 127.0;
    s_ws = ws;
    if (isq) outs_q[r] = ws * (double)s_in_p[0];
    else     wsp[r - kOC] = ws;
  }
  __syncthreads();
  double ws = s_ws;
  int8_t* dA = isq ? wq8A + (size_t)r * kC : wp8A + (size_t)(r - kOC) * kC;
  int8_t* dB = isq ? wq8B + (size_t)r * kC : wp8B + (size_t)(r - kOC) * kC;
  for (int i = threadIdx.x; i < kC; i += 256) {
    double arg = (double)row[i] / ws;
    int vA = (int)fmin(fmax(rint(arg - kEpsW), -128.0), 127.0);
    int vB = (int)fmin(fmax(rint(arg + kEpsW), -128.0), 127.0);
    dA[i] = (int8_t)vA;
    dB[i] = (int8_t)vB;
    if (isq && vA != vB) {
      int idx = atomicAdd((int*)(ctl + 12), 1);
      if (idx < kMaxFlips) flips[idx] = make_int4(r, i, vB - vA, 0);
    }
  }
}

// ---------------- x quantization (exact, shared) ----------------
__global__ __launch_bounds__(256) void k_quant_x(
    const float* __restrict__ x, const float* __restrict__ s_in_p,
    int8_t* __restrict__ x8) {
  double s = (double)s_in_p[0];
  int total = kM * kC;
  for (int i = blockIdx.x * 256 + threadIdx.x; i < total; i += gridDim.x * 256)
    x8[i] = (int8_t)(int)rint((double)x[i] / s);
}

// ------- single GEMM1 pass (branch A weights): store C1 + hmax -------
__global__ __launch_bounds__(256) void k_gemm1c(
    const int8_t* __restrict__ A, const int8_t* __restrict__ Bm,
    const double* __restrict__ outs_q, char* __restrict__ ctl,
    int* __restrict__ C1) {
  __shared__ __align__(16) int8_t As[128][80];
  __shared__ __align__(16) int8_t Bs[128][80];
  int bm = blockIdx.y * 128, bn = blockIdx.x * 128;
  int tid = threadIdx.x;
  int w = tid >> 6, l = tid & 63;
  int frow = l & 15, fk = (l >> 4) << 4;
  int rb = w * 32;
  i32x4 acc[2][8];
#pragma unroll
  for (int i = 0; i < 2; ++i)
#pragma unroll
    for (int s = 0; s < 8; ++s) { acc[i][s][0]=0; acc[i][s][1]=0; acc[i][s][2]=0; acc[i][s][3]=0; }
  for (int k0 = 0; k0 < kC; k0 += 64) {
    __syncthreads();
#pragma unroll
    for (int e = 0; e < 2; ++e) {
      int idx = tid + e * 256;
      int row = idx >> 2, cg = (idx & 3) << 4;
      *(int4*)&As[row][cg] = *(const int4*)&A[(size_t)(bm + row) * kC + k0 + cg];
      *(int4*)&Bs[row][cg] = *(const int4*)&Bm[(size_t)(bn + row) * kC + k0 + cg];
    }
    __syncthreads();
    i32x4 af0 = *(const i32x4*)&As[rb + frow][fk];
    i32x4 af1 = *(const i32x4*)&As[rb + 16 + frow][fk];
#pragma unroll
    for (int s = 0; s < 8; ++s) {
      i32x4 bf = *(const i32x4*)&Bs[s * 16 + frow][fk];
      mfma_i8_acc(acc[0][s], af0, bf);
      mfma_i8_acc(acc[1][s], af1, bf);
    }
  }
  double m = 0.0;
#pragma unroll
  for (int s = 0; s < 8; ++s) {
    int o = bn + s * 16 + frow;
    double oq = outs_q[o];
#pragma unroll
    for (int i = 0; i < 2; ++i)
#pragma unroll
      for (int r = 0; r < 4; ++r) {
        int n = bm + rb + i * 16 + ((l >> 4) << 2) + r;
        int v = acc[i][s][r];
        C1[(size_t)n * kOC + o] = v;
        m = fmax(m, fabs((double)v * oq));
      }
  }
  m = wave_max_d(m);
  __shared__ double sred[4];
  if (l == 0) sred[w] = m;
  __syncthreads();
  if (tid == 0) {
    double mm = fmax(fmax(sred[0], sred[1]), fmax(sred[2], sred[3]));
    atomicMax((unsigned long long*)ctl,
              (unsigned long long)__double_as_longlong(mm));
  }
}

// ------- build unique flipped-column map (single thread; tiny) -------
__global__ void k_colmap(char* __restrict__ ctl, const int4* __restrict__ flips,
                         short* __restrict__ colmap, int* __restrict__ ucol) {
  if (threadIdx.x != 0 || blockIdx.x != 0) return;
  int cnt = min(*(const int*)(ctl + 12), kMaxFlips);
  int u = 0;
  for (int f = 0; f < cnt; ++f) {
    int o = flips[f].x;
    if (colmap[o] < 0 && u < kMaxUCols) { colmap[o] = (short)u; ucol[u] = o; ++u; }
  }
  *(int*)(ctl + 32) = u;
}

// ------- accumulate sparse column corrections: Ccorr[n][u] += x8[n][i]*delta -------
__global__ __launch_bounds__(256) void k_colfix(
    const char* __restrict__ ctl, const int4* __restrict__ flips,
    const short* __restrict__ colmap, const int8_t* __restrict__ x8,
    int* __restrict__ Ccorr) {
  int cnt = min(*(const int*)(ctl + 12), kMaxFlips);
  for (int f = blockIdx.x; f < cnt; f += gridDim.x) {
    int o = flips[f].x, i = flips[f].y, d = flips[f].z;
    int u = colmap[o];
    if (u < 0) continue;
    for (int n = threadIdx.x; n < kM; n += 256)
      atomicAdd(&Ccorr[(size_t)n * kMaxUCols + u], d * (int)x8[(size_t)n * kC + i]);
  }
}

// ------- hmax contribution of branch-B flipped columns -------
__global__ __launch_bounds__(256) void k_colmax(
    char* __restrict__ ctl, const int* __restrict__ ucol,
    const int* __restrict__ C1, const int* __restrict__ Ccorr,
    const double* __restrict__ outs_q) {
  int u = blockIdx.x;
  if (u >= *(const int*)(ctl + 32)) return;
  int o = ucol[u];
  double oq = outs_q[o];
  double m = 0.0;
  for (int n = threadIdx.x; n < kM; n += 256) {
    int c = C1[(size_t)n * kOC + o] + Ccorr[(size_t)n * kMaxUCols + u];
    m = fmax(m, fabs((double)c * oq));
  }
  m = wave_max_d(m);
  __shared__ double sred[4];
  if ((threadIdx.x & 63) == 0) sred[threadIdx.x >> 6] = m;
  __syncthreads();
  if (threadIdx.x == 0) {
    double mm = fmax(fmax(sred[0], sred[1]), fmax(sred[2], sred[3]));
    atomicMax((unsigned long long*)ctl,
              (unsigned long long)__double_as_longlong(mm));
  }
}

// ------- elementwise h quantization (BR=0: A, BR=1: B via sparse corr) -------
template <int BR>
__global__ __launch_bounds__(256) void k_quant_h(
    const int* __restrict__ C1, const int* __restrict__ Ccorr,
    const short* __restrict__ colmap, const double* __restrict__ outs_q,
    const char* __restrict__ ctl, int8_t* __restrict__ qkv8,
    int8_t* __restrict__ vT8, double dit) {
  double s1 = get_s1(ctl);
  double inv_s1 = 1.0 / s1;
  int total = kM * kOC;
  for (int i = blockIdx.x * 256 + threadIdx.x; i < total; i += gridDim.x * 256) {
    int n = i / kOC, o = i - n * kOC;
    int c = C1[i];
    if (BR) {
      int u = colmap[o];
      if (u >= 0) c += Ccorr[(size_t)n * kMaxUCols + u];
    }
    double num = (double)c * outs_q[o];
    double t = num * inv_s1 + dit;
    double r0 = rint(t);
    if (0.5 - fabs(t - r0) < kGuard) {
      t = num / s1 + dit;
      r0 = rint(t);
    }
    double v = fmin(fmax(r0, -128.0), 127.0);
    int which = o / kC, rem = o - which * kC;
    int hh = rem >> 6, dd = rem & 63;
    int bb = n / kN, nn = n - bb * kN;
    int8_t q8v = (int8_t)(int)v;
    qkv8[(size_t)which * SZ_QKV1 + (((size_t)bb * kH + hh) * kN + nn) * kD + dd] = q8v;
    if (which == 2)
      vT8[((size_t)(bb * kH + hh) * kD + dd) * kNp + nn] = q8v;
  }
}

// ---------------- 128x128 MFMA proj GEMM (exact int32) ----------------
__global__ __launch_bounds__(256) void k_gemm_i8m(
    const int8_t* __restrict__ A, const int8_t* __restrict__ Bm,
    int* __restrict__ Cout, int Ncols, int K) {
  __shared__ __align__(16) int8_t As[128][80];
  __shared__ __align__(16) int8_t Bs[128][80];
  int bm = blockIdx.y * 128, bn = blockIdx.x * 128;
  int tid = threadIdx.x;
  int w = tid >> 6, l = tid & 63;
  int frow = l & 15, fk = (l >> 4) << 4;
  int rb = w * 32;
  i32x4 acc[2][8];
#pragma unroll
  for (int i = 0; i < 2; ++i)
#pragma unroll
    for (int s = 0; s < 8; ++s) { acc[i][s][0]=0; acc[i][s][1]=0; acc[i][s][2]=0; acc[i][s][3]=0; }
  for (int k0 = 0; k0 < K; k0 += 64) {
    __syncthreads();
#pragma unroll
    for (int e = 0; e < 2; ++e) {
      int idx = tid + e * 256;
      int row = idx >> 2, cg = (idx & 3) << 4;
      *(int4*)&As[row][cg] = *(const int4*)&A[(size_t)(bm + row) * K + k0 + cg];
      *(int4*)&Bs[row][cg] = *(const int4*)&Bm[(size_t)(bn + row) * K + k0 + cg];
    }
    __syncthreads();
    i32x4 af0 = *(const i32x4*)&As[rb + frow][fk];
    i32x4 af1 = *(const i32x4*)&As[rb + 16 + frow][fk];
#pragma unroll
    for (int s = 0; s < 8; ++s) {
      i32x4 bf = *(const i32x4*)&Bs[s * 16 + frow][fk];
      mfma_i8_acc(acc[0][s], af0, bf);
      mfma_i8_acc(acc[1][s], af1, bf);
    }
  }
#pragma unroll
  for (int s = 0; s < 8; ++s) {
    int n = bn + s * 16 + frow;
#pragma unroll
    for (int i = 0; i < 2; ++i)
#pragma unroll
      for (int r = 0; r < 4; ++r) {
        int m = bm + rb + i * 16 + ((l >> 4) << 2) + r;
        Cout[(size_t)m * Ncols + n] = acc[i][s][r];
      }
  }
}

// ------- global max |q.k| v2: one block per bh, K-plane in LDS (exact max) -------
__global__ __launch_bounds__(256) void k_qkmax2(
    const int8_t* __restrict__ qkv8, char* __restrict__ ctl) {
  int bh = blockIdx.x;
  const int8_t* qb = qkv8 + (size_t)bh * kN * kD;
  const int8_t* kb = qkv8 + SZ_QKV1 + (size_t)bh * kN * kD;
  __shared__ __align__(16) int8_t KS[784][80];
  int tid = threadIdx.x;
  for (int idx = tid; idx < 3136; idx += 256) {
    int row = idx >> 2, c16 = (idx & 3) << 4;
    *(int4*)&KS[row][c16] = *(const int4*)&kb[(size_t)row * kD + c16];
  }
  __syncthreads();
  int w = tid >> 6, l = tid & 63;
  int frow = l & 15, fk = (l >> 4) << 4;
  int mx = 0;
  for (int nt = w; nt < 49; nt += 4) {
    i32x4 af = *(const i32x4*)&qb[(size_t)(nt * 16 + frow) * kD + fk];
#pragma unroll 7
    for (int mt = 0; mt < 49; ++mt) {
      i32x4 bf = *(const i32x4*)&KS[mt * 16 + frow][fk];
      i32x4 c; c[0] = 0; c[1] = 0; c[2] = 0; c[3] = 0;
      mfma_i8_acc(c, af, bf);
      mx = max(mx, max(max(abs(c[0]), abs(c[1])), max(abs(c[2]), abs(c[3]))));
    }
  }
  mx = wave_max_i(mx);
  __shared__ int sred[4];
  if (l == 0) sred[w] = mx;
  __syncthreads();
  if (tid == 0) {
    int mm = max(max(sred[0], sred[1]), max(sred[2], sred[3]));
    atomicMax((int*)(ctl + 8), mm);
  }
}

// --- fused attn per branch (QBLK=16): MFMA QK^T + int softmax + MFMA PV ---
__global__ __launch_bounds__(256) void k_attn(
    const int8_t* __restrict__ q8, const int8_t* __restrict__ k8,
    const int8_t* __restrict__ vT8, char* __restrict__ ctl,
    float* __restrict__ pv, double dit, double x0dit) {
  double s1 = get_s1(ctl);
  double s1s1 = s1 * s1;
  double s_a = get_sa(ctl);
  double inv_sa = 1.0 / s_a;
  double cfast = (s1s1 * 0.125) * inv_sa;           // fast-path constant
  double x0 = floor(-1.0 / s_a + x0dit);
  int x0i = (int)x0;
  int dpos = -x0i;
  unsigned long long magicM =
      (0x100000000ULL + (unsigned long long)(dpos - 1)) / (unsigned long long)dpos;
  int m15 = 15 * x0i;

  int bh = blockIdx.y;
  int n0 = blockIdx.x * 16;
  int bb = bh / kH, hh = bh % kH;
  const int8_t* kb = k8 + (size_t)bh * kN * kD;

  __shared__ __align__(16) int8_t Qs[16][64];
  __shared__ __align__(16) int8_t PL[3][16][848];   // PL[0] doubles as AQ

  int tid = threadIdx.x;
  int w = tid >> 6, l = tid & 63;

  // load Q tile (16 rows x 64B)
  {
    int row = tid >> 4, c4 = (tid & 15) << 2;
    *(int*)&Qs[row][c4] =
        *(const int*)&q8[((size_t)bh * kN + n0 + row) * kD + c4];
  }
  __syncthreads();

  // phase 1: MFMA QK^T -> quantized attn ints into PL[0]
  {
    int frow = l & 15, fk = (l >> 4) << 4;
    i32x4 af = *(const i32x4*)&Qs[frow][fk];
    for (int t = w; t < 49; t += 4) {
      int m0 = t * 16;
      i32x4 bf = *(const i32x4*)&kb[(size_t)(m0 + frow) * kD + fk];
      i32x4 c; c[0] = 0; c[1] = 0; c[2] = 0; c[3] = 0;
      mfma_i8_acc(c, af, bf);
#pragma unroll
      for (int r = 0; r < 4; ++r) {
        int q = ((l >> 4) << 2) + r;
        double t_f = (double)c[r] * cfast + dit;     // fast path
        double r0 = rint(t_f);
        if (0.5 - fabs(t_f - r0) < kGuard) {          // boundary: exact chain
          double attnv = ((double)c[r] * s1s1) * 0.125;
          r0 = rint(attnv / s_a + dit);
        }
        double aq = fmin(fmax(r0, -128.0), 127.0);
        PL[0][q][m0 + frow] = (int8_t)(int)aq;
      }
    }
  }
  __syncthreads();

  // phase 2: integer int_softmax -> digit planes (magic-div p_eval)
  {
    int lane = l;
    for (int rr = 0; rr < 4; ++rr) {
      int row = w * 4 + rr;
      int rmax = -128;
#pragma unroll
      for (int i = 0; i < 13; ++i) {
        int m = lane + i * 64;
        if (m < kN) rmax = max(rmax, (int)(int8_t)PL[0][row][m]);
      }
      rmax = wave_max_i(rmax);
      int parr[13];
      long long sd = 0;
#pragma unroll
      for (int i = 0; i < 13; ++i) {
        int m = lane + i * 64;
        int p = 0;
        if (m < kN) {
          p = p_eval_m((int)(int8_t)PL[0][row][m] - rmax, x0i, m15, magicM);
          sd += p;
        }
        parr[i] = p;
      }
      for (int off = 32; off; off >>= 1) sd += __shfl_xor(sd, off);
      long long S = sd > 2147483647LL ? 2147483647LL : sd;
      long long SLo = S + kDS;
      long long SHi = S - kDS; if (SHi < 1) SHi = 1;
      if (SLo > 2147483647LL) SLo = 2147483647LL;
      long long fLo = (long long)(2147483647u / (unsigned)SLo);
      long long fHi = (long long)(2147483647u / (unsigned)SHi);
#pragma unroll
      for (int i = 0; i < 13; ++i) {
        int m = lane + i * 64;
        if (m < kN) {
          int p4 = p4_final((long long)parr[i], fLo, fHi);
          int b0 = (int)(int8_t)(p4 & 0xff);
          int t1 = (p4 - b0) >> 8;
          int b1 = (int)(int8_t)(t1 & 0xff);
          int b2 = (t1 - b1) >> 8;
          PL[0][row][m] = (int8_t)b0;
          PL[1][row][m] = (int8_t)b1;
          PL[2][row][m] = (int8_t)b2;
        }
      }
      for (int m = kN + lane; m < 832; m += 64) {
        PL[0][row][m] = 0; PL[1][row][m] = 0; PL[2][row][m] = 0;
      }
    }
  }
  __syncthreads();

  // phase 3: MFMA PV — per wave one 16-d subtile; 16 valid q rows.
  {
    int frow = l & 15;
    int fk = (l >> 4) << 4;
    int dglob = w * 16 + frow;
    const int8_t* vtb = vT8 + ((size_t)bh * kD + dglob) * kNp;
    i32x4 a0, a1, a2;
    a0[0]=0;a0[1]=0;a0[2]=0;a0[3]=0;
    a1[0]=0;a1[1]=0;a1[2]=0;a1[3]=0;
    a2[0]=0;a2[1]=0;a2[2]=0;a2[3]=0;
    for (int mt = 0; mt < 13; ++mt) {
      int m0 = mt * 64;
      i32x4 bf = *(const i32x4*)&vtb[m0 + fk];
      i32x4 f0 = *(const i32x4*)&PL[0][frow][m0 + fk];
      i32x4 f1 = *(const i32x4*)&PL[1][frow][m0 + fk];
      i32x4 f2 = *(const i32x4*)&PL[2][frow][m0 + fk];
      mfma_i8_acc(a0, f0, bf);
      mfma_i8_acc(a1, f1, bf);
      mfma_i8_acc(a2, f2, bf);
    }
    double mymax = 0.0;
    int qhi = l >> 4;
#pragma unroll
    for (int r = 0; r < 4; ++r) {
      int q = qhi * 4 + r;
      long long tot = (long long)a0[r] + ((long long)a1[r] << 8) +
                      ((long long)a2[r] << 16);
      double v = 0.25 * (double)tot;
      pv[((size_t)bb * kN + (n0 + q)) * kC + hh * kD + dglob] = (float)v;
      mymax = fmax(mymax, fabs(v));
    }
    mymax = wave_max_d(mymax);
    __shared__ double sredd[4];
    if (l == 0) sredd[w] = mymax;
    __syncthreads();
    if (tid == 0) {
      double mm = fmax(fmax(sredd[0], sredd[1]), fmax(sredd[2], sredd[3]));
      atomicMax((unsigned long long*)(ctl + 24),
                (unsigned long long)__double_as_longlong(mm));
    }
  }
}

// ---------------- per-column precompute: outs, bint (A and B) ----------------
__global__ __launch_bounds__(256) void k_prep(
    const double* __restrict__ wsp, const float* __restrict__ bias,
    const char* __restrict__ ctl, double* __restrict__ outsv,
    double* __restrict__ bintA, double* __restrict__ bintB) {
  double s_o = get_so(ctl);
  int o = blockIdx.x * 256 + threadIdx.x;
  if (o < kC) {
    double outs = wsp[o] * s_o;
    outsv[o] = outs;
    double base = (double)bias[o] / outs;
    bintA[o] = rint(base - kEps);
    bintB[o] = rint(base + kEps);
  }
}

// ---------------- quantize attn output per branch (guarded fast path) ----------------
__global__ __launch_bounds__(256) void k_quant_o(
    const float* __restrict__ pv, const char* __restrict__ ctl,
    int8_t* __restrict__ o8, double dit) {
  double c2 = get_c2(ctl);
  double s_o = get_so(ctl);
  double inv_so = 1.0 / s_o;
  int total = kM * kC;
  for (int i = blockIdx.x * 256 + threadIdx.x; i < total; i += gridDim.x * 256) {
    double num = (double)pv[i] * c2;
    double t = num * inv_so + dit;
    double r0 = rint(t);
    if (0.5 - fabs(t - r0) < kGuard) r0 = rint(num / s_o + dit);
    double v = fmin(fmax(r0, -128.0), 127.0);
    o8[i] = (int8_t)(int)v;
  }
}

// ---------------- proj bias + max per branch (precomputed bint/outs) ----------------
__global__ __launch_bounds__(256) void k_bias_max(
    int* __restrict__ p2, const double* __restrict__ outsv,
    const double* __restrict__ bint, char* __restrict__ ctl) {
  int n = blockIdx.x;
  int* rowp = p2 + (size_t)n * kC;
  double m = 0.0;
  for (int o = threadIdx.x; o < kC; o += 256) {
    int a = rowp[o] + (int)bint[o];
    rowp[o] = a;
    m = fmax(m, fabs((double)a * outsv[o]));
  }
  m = wave_max_d(m);
  __shared__ double sred[4];
  if ((threadIdx.x & 63) == 0) sred[threadIdx.x >> 6] = m;
  __syncthreads();
  if (threadIdx.x == 0) {
    double mm = fmax(fmax(sred[0], sred[1]), fmax(sred[2], sred[3]));
    atomicMax((unsigned long long*)(ctl + 16),
              (unsigned long long)__double_as_longlong(mm));
  }
}

// ---------------- final: branch midpoint ----------------
__global__ __launch_bounds__(256) void k_final(
    const int* __restrict__ p2A, const int* __restrict__ p2B,
    const double* __restrict__ outsv,
    const char* __restrict__ ctl, float* __restrict__ out) {
  double s_out = ctl_pmax(ctl) / 32767.0;
  int total = kM * kC;
  for (int i = blockIdx.x * 256 + threadIdx.x; i < total; i += gridDim.x * 256) {
    int o = i % kC;
    double outs = outsv[o];
    double vA = fmin(fmax(rint(((double)p2A[i] * outs) / s_out - kEps), -32768.0), 32767.0);
    double vB = fmin(fmax(rint(((double)p2B[i] * outs) / s_out + kEps), -32768.0), 32767.0);
    out[i] = (float)(0.5 * (vA + vB) * s_out);
  }
  if (blockIdx.x == 0 && threadIdx.x == 0) out[total] = (float)s_out;
}

}  // namespace

extern "C" void kernel_launch(void* const* d_in, const int* in_sizes, int n_in,
                              void* d_out, int out_size, void* d_ws, size_t ws_size,
                              hipStream_t stream) {
  const float* x   = (const float*)d_in[0];
  const float* sin = (const float*)d_in[1];
  const float* Wq  = (const float*)d_in[2];
  const float* Wp  = (const float*)d_in[3];
  const float* bp  = (const float*)d_in[4];
  float* out = (float*)d_out;

  char* ws = (char*)d_ws;
  char* ctl = ws;
  size_t off = 1024;
  int4*  flips  = (int4*)(ws + off);  off += (size_t)kMaxFlips * 16;
  short* colmap = (short*)(ws + off); off += (size_t)kOC * 2;
  off = (off + 255) & ~(size_t)255;
  int*   ucol   = (int*)(ws + off);   off += (size_t)kMaxUCols * 4;
  off = (off + 255) & ~(size_t)255;
  int8_t* x8   = (int8_t*)(ws + off); off += (size_t)kM * kC;
  int8_t* wq8A = (int8_t*)(ws + off); off += (size_t)kOC * kC;
  int8_t* wq8B = (int8_t*)(ws + off); off += (size_t)kOC * kC;
  int8_t* wp8A = (int8_t*)(ws + off); off += (size_t)kC * kC;
  int8_t* wp8B = (int8_t*)(ws + off); off += (size_t)kC * kC;
  off = (off + 255) & ~(size_t)255;
  double* outs_q = (double*)(ws + off); off += (size_t)kOC * 8;
  double* wsp    = (double*)(ws + off); off += (size_t)kC * 8;
  double* outsv  = (double*)(ws + off); off += (size_t)kC * 8;
  double* bintA  = (double*)(ws + off); off += (size_t)kC * 8;
  double* bintB  = (double*)(ws + off); off += (size_t)kC * 8;
  off = (off + 255) & ~(size_t)255;
  int8_t* qkvA = (int8_t*)(ws + off); off += 3 * SZ_QKV1;
  int8_t* qkvB = (int8_t*)(ws + off); off += 3 * SZ_QKV1;
  int8_t* qA = qkvA, *kA = qkvA + SZ_QKV1;
  int8_t* qB = qkvB, *kB = qkvB + SZ_QKV1;
  off = (off + 255) & ~(size_t)255;
  int8_t* vT8A = (int8_t*)(ws + off); off += SZ_VT;
  int8_t* vT8B = (int8_t*)(ws + off); off += SZ_VT;
  int8_t* o8A = (int8_t*)(ws + off); off += (size_t)kM * kC;
  int8_t* o8B = (int8_t*)(ws + off); off += (size_t)kM * kC;
  off = (off + 255) & ~(size_t)255;
  int* Ccorr = (int*)(ws + off); off += (size_t)kM * kMaxUCols * 4;
  off = (off + 255) & ~(size_t)255;
  int* C1A = (int*)(ws + off); off += (size_t)kM * kOC * 4;
  // pv/p2 overlay C1A after its last read (k_quant_h<1>)
  float* pvA = (float*)C1A;                 int* p2A = (int*)pvA;
  float* pvB = (float*)((char*)C1A + (size_t)kM * kC * 4); int* p2B = (int*)pvB;

  dim3 g1(kOC / 128, kM / 128);
  hipMemsetAsync(ctl, 0, 1024, stream);
  hipMemsetAsync(colmap, 0xFF, (size_t)kOC * 2, stream);
  hipMemsetAsync(Ccorr, 0, (size_t)kM * kMaxUCols * 4, stream);
  k_quant_w<<<kOC + kC, 256, 0, stream>>>(Wq, Wp, sin, wq8A, wq8B, wp8A, wp8B,
                                          outs_q, wsp, ctl, flips);
  k_quant_x<<<2048, 256, 0, stream>>>(x, sin, x8);
  k_gemm1c<<<g1, 256, 0, stream>>>(x8, wq8A, outs_q, ctl, C1A);
  k_colmap<<<1, 64, 0, stream>>>(ctl, flips, colmap, ucol);
  k_colfix<<<256, 256, 0, stream>>>(ctl, flips, colmap, x8, Ccorr);
  k_colmax<<<kMaxUCols, 256, 0, stream>>>(ctl, ucol, C1A, Ccorr, outs_q);
  k_quant_h<0><<<2048, 256, 0, stream>>>(C1A, Ccorr, colmap, outs_q, ctl,
                                         qkvA, vT8A, -kEps);
  k_quant_h<1><<<2048, 256, 0, stream>>>(C1A, Ccorr, colmap, outs_q, ctl,
                                         qkvB, vT8B, +kEps);
  k_qkmax2<<<kBH, 256, 0, stream>>>(qkvA, ctl);
  k_qkmax2<<<kBH, 256, 0, stream>>>(qkvB, ctl);
  k_attn<<<dim3(49, kBH), 256, 0, stream>>>(qA, kA, vT8A, ctl, pvA, -kEps, -kEpsX0);
  k_attn<<<dim3(49, kBH), 256, 0, stream>>>(qB, kB, vT8B, ctl, pvB, +kEps, +kEpsX0);
  k_prep<<<3, 256, 0, stream>>>(wsp, bp, ctl, outsv, bintA, bintB);
  k_quant_o<<<2048, 256, 0, stream>>>(pvA, ctl, o8A, -kEps);
  k_quant_o<<<2048, 256, 0, stream>>>(pvB, ctl, o8B, +kEps);
  k_gemm_i8m<<<dim3(kC / 128, kM / 128), 256, 0, stream>>>(o8A, wp8A, p2A, kC, kC);
  k_gemm_i8m<<<dim3(kC / 128, kM / 128), 256, 0, stream>>>(o8B, wp8B, p2B, kC, kC);
  k_bias_max<<<kM, 256, 0, stream>>>(p2A, outsv, bintA, ctl);
  k_bias_max<<<kM, 256, 0, stream>>>(p2B, outsv, bintB, ctl);
  k_final<<<2048, 256, 0, stream>>>(p2A, p2B, outsv, ctl, out);
}